// Round 16
// baseline (548.874 us; speedup 1.0000x reference)
//
#include <hip/hip_runtime.h>
#include <math.h>

#define N_NODES 50000
#define N_EDGES 600000
#define F_INPUT 128
#define HCDIM 256
#define NGRAPH 64
#define NCLS 3
#define MPAD 50048   // 782 * 64, GEMM M padded
#define SCAN_NB ((N_NODES + 255) / 256)   // 196
#define LOG2E 1.4426950408889634f
#define NPART 32     // pooling partitions per graph

// fused prep kernel block ranges
#define SPLITX_NB (MPAD * F_INPUT / 4 / 256)            // 6256
#define ZERO_NB   (((MPAD - N_NODES) * HCDIM / 4 + 255) / 256)  // 12
#define WPREP_NB  (512 * (F_INPUT + HCDIM + HCDIM) / 256)       // 1280
#define PREP_NB   (SPLITX_NB + ZERO_NB + WPREP_NB)
// fused hist+boundary ranges
#define HIST_NB   ((N_EDGES + N_NODES + 255) / 256)     // 2540
#define BND_NB    ((N_NODES + 255) / 256)               // 196

typedef float f32x4 __attribute__((ext_vector_type(4)));
typedef float f32x2 __attribute__((ext_vector_type(2)));
typedef _Float16 f16x8 __attribute__((ext_vector_type(8)));
typedef _Float16 f16x4 __attribute__((ext_vector_type(4)));
typedef _Float16 h2 __attribute__((ext_vector_type(2)));

__device__ __forceinline__ h2 bch2(unsigned int u) { return __builtin_bit_cast(h2, u); }
__device__ __forceinline__ h2 pk16(float a, float b) {
    return __builtin_bit_cast(h2, __builtin_amdgcn_cvt_pkrtz(a, b));
}

// packed leaky_relu(0.2): max(v,0) + 0.2*min(v,0)
__device__ __forceinline__ h2 lrelu2(h2 v) {
    const h2 z = {(_Float16)0.f, (_Float16)0.f};
    const h2 c = {(_Float16)0.2f, (_Float16)0.2f};
    h2 mx = __builtin_elementwise_max(v, z);
    h2 mn = __builtin_elementwise_min(v, z);
    return mx + mn * c;
}

// ============================ hist + boundary (fused) ============================
__global__ void hist_boundary_kernel(const int* __restrict__ ei, int* __restrict__ deg,
                                     const int* __restrict__ batch,
                                     int* __restrict__ startg, int* __restrict__ endg) {
    int b = blockIdx.x;
    if (b < HIST_NB) {
        int i = b * 256 + threadIdx.x;
        int total = N_EDGES + N_NODES;
        if (i >= total) return;
        int d = (i < N_EDGES) ? ei[N_EDGES + i] : (i - N_EDGES);
        atomicAdd(&deg[d], 1);
    } else {
        int i = (b - HIST_NB) * 256 + threadIdx.x;
        if (i >= N_NODES) return;
        int g = batch[i];
        if (i == 0 || batch[i - 1] != g) startg[g] = i;
        if (i == N_NODES - 1 || batch[i + 1] != g) endg[g] = i + 1;
    }
}

// ============================ CSR scan ============================
__global__ void block_scan_kernel(const int* __restrict__ deg, int* __restrict__ rowptr,
                                  int* __restrict__ bsums) {
    __shared__ int wt[4];
    int b = blockIdx.x, t = threadIdx.x, lane = t & 63, wid = t >> 6;
    int i = b * 256 + t;
    int v = (i < N_NODES) ? deg[i] : 0;
    int x = v;
    #pragma unroll
    for (int off = 1; off < 64; off <<= 1) {
        int y = __shfl_up(x, off, 64);
        if (lane >= off) x += y;
    }
    if (lane == 63) wt[wid] = x;
    __syncthreads();
    if (t == 0) {
        int s = 0;
        #pragma unroll
        for (int j = 0; j < 4; ++j) { int tv = wt[j]; wt[j] = s; s += tv; }
        bsums[b] = s;
    }
    __syncthreads();
    if (i < N_NODES) rowptr[i] = wt[wid] + x - v;
}

// add_off with in-block bsums prefix
__global__ void add_off_kernel(int* __restrict__ rowptr, int* __restrict__ cursor,
                               const int* __restrict__ bsums) {
    __shared__ int red[256];
    int b = blockIdx.x, t = threadIdx.x;
    red[t] = (t < b) ? bsums[t] : 0;   // b <= SCAN_NB-1 < 256
    __syncthreads();
    for (int off = 128; off > 0; off >>= 1) {
        if (t < off) red[t] += red[t + off];
        __syncthreads();
    }
    int offv = red[0];
    int i = b * 256 + t;
    if (i < N_NODES) {
        int r = rowptr[i] + offv;
        rowptr[i] = r;
        cursor[i] = r;
    }
    if (i == 0) rowptr[N_NODES] = N_EDGES + N_NODES;
}

// colx stores BYTE offsets into the fp8 xl matrix: s * HCDIM (256 B rows).
// Entries [total, total+8) are zero padding so the edge loop needs no prefetch clamps.
__global__ void fill_kernel(const int* __restrict__ ei, int* __restrict__ cursor,
                            int* __restrict__ colx) {
    int i = blockIdx.x * 256 + threadIdx.x;
    int total = N_EDGES + N_NODES;
    if (i >= total + 8) return;
    if (i >= total) { colx[i] = 0; return; }
    int s, d;
    if (i < N_EDGES) { s = ei[i]; d = ei[N_EDGES + i]; }
    else             { s = i - N_EDGES; d = s; }
    int pos = atomicAdd(&cursor[d], 1);
    colx[pos] = s * HCDIM;
}

// ============================ Fused prep: x->fp16, pad zero, W->fp16 n-major ============================
__global__ void prep_kernel(const float* __restrict__ x, _Float16* __restrict__ A,
                            _Float16* __restrict__ Bt0, _Float16* __restrict__ Bt1,
                            _Float16* __restrict__ Bt2,
                            const float* __restrict__ Wl0, const float* __restrict__ Wr0,
                            const float* __restrict__ Wl1, const float* __restrict__ Wr1,
                            const float* __restrict__ Wl2, const float* __restrict__ Wr2) {
    int b = blockIdx.x;
    if (b < SPLITX_NB) {
        int base = (b * 256 + threadIdx.x) * 4;
        int row = base >> 7;
        float4 v = make_float4(0.f, 0.f, 0.f, 0.f);
        if (row < N_NODES) v = *(const float4*)&x[base];
        f16x4 o;
        o.x = (_Float16)v.x; o.y = (_Float16)v.y; o.z = (_Float16)v.z; o.w = (_Float16)v.w;
        *(f16x4*)&A[base] = o;
    } else if (b < SPLITX_NB + ZERO_NB) {
        int i = ((b - SPLITX_NB) * 256 + threadIdx.x) * 4;
        if (i < (MPAD - N_NODES) * HCDIM) {
            f16x4 z = {(_Float16)0.f, (_Float16)0.f, (_Float16)0.f, (_Float16)0.f};
            *(f16x4*)&A[(size_t)N_NODES * HCDIM + i] = z;
        }
    } else {
        int t = (b - SPLITX_NB - ZERO_NB) * 256 + threadIdx.x;
        const float* Wl; const float* Wr; _Float16* Bt; int K;
        if (t < 512 * F_INPUT)            { Wl = Wl0; Wr = Wr0; Bt = Bt0; K = F_INPUT; }
        else if (t < 512 * (F_INPUT + HCDIM)) { t -= 512 * F_INPUT; Wl = Wl1; Wr = Wr1; Bt = Bt1; K = HCDIM; }
        else                              { t -= 512 * (F_INPUT + HCDIM); Wl = Wl2; Wr = Wr2; Bt = Bt2; K = HCDIM; }
        int n = t & 511, k = t >> 9;
        float w = (n < 256) ? Wl[k * 256 + n] : Wr[k * 256 + (n - 256)];
        Bt[n * K + k] = (_Float16)w;
    }
}

// ============================ LDS-free fp16 MFMA GEMM, 64x128 tile ============================
// No input staging: A fragments stream from global (line-perfect: a wave covers 16 rows x 64 B),
// B (256 KB total) stays hot in L2/L3. K-loop = 6 dwordx4 loads + 8 MFMA, ZERO barriers ->
// pure TLP hides latency (the barrier-drain serialization of the staged version is gone).
// LDS (16 KB) used only to transpose the epilogue: stage C tile, reload row-major, store wide
// (fixes the 1.7x write amplification from scattered 1-2 B stores).
__global__ __launch_bounds__(256) void gemm_mfma(
    const _Float16* __restrict__ A, const _Float16* __restrict__ B,
    int K,
    const float* __restrict__ bl, const float* __restrict__ br,
    unsigned char* __restrict__ xl8, _Float16* __restrict__ xrh)
{
    __shared__ char sC[16384];
    int tid = threadIdx.x;
    int lane = tid & 63, wave = tid >> 6;
    int wm = wave >> 1, wn = wave & 1;
    int bx = blockIdx.x >> 2, by = blockIdx.x & 3;
    int row0 = bx * 64, n0 = by * 128;
    int quad = lane >> 4, l16 = lane & 15;

    const _Float16* Ar0 = A + (size_t)(row0 + wm * 32 + l16) * K + quad * 8;
    const _Float16* Ar1 = Ar0 + (size_t)16 * K;
    const _Float16* Br[4];
    #pragma unroll
    for (int j = 0; j < 4; ++j)
        Br[j] = B + (size_t)(n0 + wn * 64 + j * 16 + l16) * K + quad * 8;

    f32x4 acc[2][4];
    #pragma unroll
    for (int i = 0; i < 2; ++i)
        #pragma unroll
        for (int j = 0; j < 4; ++j)
            acc[i][j] = (f32x4){0.f, 0.f, 0.f, 0.f};

    for (int k0 = 0; k0 < K; k0 += 32) {
        f16x8 fa0 = *(const f16x8*)(Ar0 + k0);
        f16x8 fa1 = *(const f16x8*)(Ar1 + k0);
        f16x8 fb[4];
        #pragma unroll
        for (int j = 0; j < 4; ++j)
            fb[j] = *(const f16x8*)(Br[j] + k0);
        #pragma unroll
        for (int j = 0; j < 4; ++j) {
            acc[0][j] = __builtin_amdgcn_mfma_f32_16x16x32_f16(fa0, fb[j], acc[0][j], 0, 0, 0);
            acc[1][j] = __builtin_amdgcn_mfma_f32_16x16x32_f16(fa1, fb[j], acc[1][j], 0, 0, 0);
        }
    }

    if (by < 2) {
        // xl path: fp8, tile 64x128 = 8 KB staged in LDS
        unsigned char* s8 = (unsigned char*)sC;
        int cb0 = by * 128;
        #pragma unroll
        for (int j = 0; j < 4; ++j) {
            int coll = wn * 64 + j * 16 + l16;
            float bj = bl[cb0 + coll];
            #pragma unroll
            for (int i = 0; i < 2; ++i) {
                int rl = wm * 32 + i * 16 + quad * 4;
                #pragma unroll
                for (int r = 0; r < 4; ++r) {
                    float v = acc[i][j][r] + bj;
                    s8[(rl + r) * 128 + coll] =
                        (unsigned char)__builtin_amdgcn_cvt_pk_fp8_f32(v, v, 0, false);
                }
            }
        }
        __syncthreads();
        int rl = tid >> 2, seg = (tid & 3) * 32;     // 64 rows x 128 B, 32 B/thread
        int grow = row0 + rl;
        if (grow < N_NODES) {
            uint4 v0 = *(const uint4*)&s8[rl * 128 + seg];
            uint4 v1 = *(const uint4*)&s8[rl * 128 + seg + 16];
            *(uint4*)&xl8[(size_t)grow * HCDIM + cb0 + seg] = v0;
            *(uint4*)&xl8[(size_t)grow * HCDIM + cb0 + seg + 16] = v1;
        }
    } else {
        // xr path: fp16, tile 64x128 = 16 KB staged in LDS
        _Float16* s16 = (_Float16*)sC;
        int cb0 = (by - 2) * 128;
        #pragma unroll
        for (int j = 0; j < 4; ++j) {
            int coll = wn * 64 + j * 16 + l16;
            float bj = br[cb0 + coll];
            #pragma unroll
            for (int i = 0; i < 2; ++i) {
                int rl = wm * 32 + i * 16 + quad * 4;
                #pragma unroll
                for (int r = 0; r < 4; ++r)
                    s16[(rl + r) * 128 + coll] = (_Float16)(acc[i][j][r] + bj);
            }
        }
        __syncthreads();
        int rl = tid >> 2, segE = (tid & 3) * 32;    // 64 rows x 128 elems, 32 elems (64 B)/thread
        int grow = row0 + rl;
        if (grow < N_NODES) {
            const uint4* src = (const uint4*)&s16[rl * 128 + segE];
            uint4 a0 = src[0], a1 = src[1], a2 = src[2], a3 = src[3];
            uint4* dst = (uint4*)&xrh[(size_t)grow * HCDIM + cb0 + segE];
            dst[0] = a0; dst[1] = a1; dst[2] = a2; dst[3] = a3;
        }
    }
}

// ============================ Edge phase: quarter-wave per edge ============================
// 16 lanes per edge, 16 channels/lane (16 B fp8 = one dwordx4 gather per edge group of 4).
__global__ __launch_bounds__(256) void gat_edge(
    const unsigned char* __restrict__ xl8, const _Float16* __restrict__ xrh,
    const float* __restrict__ att, const float* __restrict__ bias,
    const int* __restrict__ rowptr, const int* __restrict__ colx,
    _Float16* __restrict__ outh, _Float16* __restrict__ onext, int mode)
{
    int wave = threadIdx.x >> 6;
    int lane = threadIdx.x & 63;
    int q  = lane >> 4;          // edge slot in group
    int ql = lane & 15;          // channel group: ch [ql*16, ql*16+16)
    int node = blockIdx.x * 4 + wave;
    if (node >= N_NODES) return;
    int cb = ql * 16;            // first channel / fp8 byte offset in row

    const char* xrrow = (const char*)xrh + (size_t)node * (HCDIM * 2) + cb * 2;
    uint4 xu0 = *(const uint4*)xrrow;
    uint4 xu1 = *(const uint4*)(xrrow + 16);
    h2 xr[8] = { bch2(xu0.x), bch2(xu0.y), bch2(xu0.z), bch2(xu0.w),
                 bch2(xu1.x), bch2(xu1.y), bch2(xu1.z), bch2(xu1.w) };
    h2 at[8];
    #pragma unroll
    for (int i = 0; i < 8; ++i) {
        float2 av = *(const float2*)&att[cb + i * 2];
        at[i] = (h2){(_Float16)(av.x * LOG2E), (_Float16)(av.y * LOG2E)};
    }

    int e0 = rowptr[node], e1 = rowptr[node + 1];
    float denom = 0.f;
    float acc[16];
    #pragma unroll
    for (int i = 0; i < 16; ++i) acc[i] = 0.f;

    uint4 d = *(const uint4*)(xl8 + (unsigned)(colx[e0 + q] + cb));

    for (int e = e0; e < e1; e += 4) {
        uint4 nd = *(const uint4*)(xl8 + (unsigned)(colx[e + 4 + q] + cb));

        unsigned int dw[4] = {d.x, d.y, d.z, d.w};
        f32x2 flo[4], fhi[4];
        h2 hx[8];
        #pragma unroll
        for (int j = 0; j < 4; ++j) {
            flo[j] = __builtin_amdgcn_cvt_pk_f32_fp8(dw[j], false);
            fhi[j] = __builtin_amdgcn_cvt_pk_f32_fp8(dw[j], true);
            hx[2 * j]     = pk16(flo[j].x, flo[j].y);
            hx[2 * j + 1] = pk16(fhi[j].x, fhi[j].y);
        }
        float pa = 0.f, pb = 0.f;
        #pragma unroll
        for (int i = 0; i < 4; ++i) {
            pa = __builtin_amdgcn_fdot2(lrelu2(hx[i] + xr[i]), at[i], pa, false);
            pb = __builtin_amdgcn_fdot2(lrelu2(hx[i + 4] + xr[i + 4]), at[i + 4], pb, false);
        }
        float p = pa + pb;
        p += __builtin_bit_cast(float, __builtin_amdgcn_ds_swizzle(__builtin_bit_cast(int, p), 0x041F));
        p += __builtin_bit_cast(float, __builtin_amdgcn_ds_swizzle(__builtin_bit_cast(int, p), 0x081F));

        float w;
        if (e + 4 <= e1) {
            w = exp2f(p);
        } else {
            w = (e + q < e1) ? exp2f(p) : 0.f;
        }
        denom += w;
        #pragma unroll
        for (int j = 0; j < 4; ++j) {
            acc[4 * j]     += w * flo[j].x;
            acc[4 * j + 1] += w * flo[j].y;
            acc[4 * j + 2] += w * fhi[j].x;
            acc[4 * j + 3] += w * fhi[j].y;
        }
        d = nd;
    }

    denom += __shfl_xor(denom, 16, 64);
    denom += __shfl_xor(denom, 32, 64);
    #pragma unroll
    for (int i = 0; i < 16; ++i) {
        acc[i] += __shfl_xor(acc[i], 16, 64);
        acc[i] += __shfl_xor(acc[i], 32, 64);
    }

    if (q == 0) {
        float inv = 1.f / denom;
        char* orow = (char*)(mode == 0 ? outh : onext) + (size_t)node * (HCDIM * 2) + cb * 2;
        h2 o[8];
        #pragma unroll
        for (int i = 0; i < 8; ++i) {
            float2 bv = *(const float2*)&bias[cb + i * 2];
            float v0 = acc[2 * i] * inv + bv.x;
            float v1 = acc[2 * i + 1] * inv + bv.y;
            if (mode != 0) { v0 = fmaxf(v0, 0.f); v1 = fmaxf(v1, 0.f); }
            o[i] = pk16(v0, v1);
        }
        uint4 s0 = { __builtin_bit_cast(unsigned int, o[0]), __builtin_bit_cast(unsigned int, o[1]),
                     __builtin_bit_cast(unsigned int, o[2]), __builtin_bit_cast(unsigned int, o[3]) };
        uint4 s1 = { __builtin_bit_cast(unsigned int, o[4]), __builtin_bit_cast(unsigned int, o[5]),
                     __builtin_bit_cast(unsigned int, o[6]), __builtin_bit_cast(unsigned int, o[7]) };
        *(uint4*)orow = s0;
        *(uint4*)(orow + 16) = s1;
    }
}

// ============================ Two-stage pooling ============================
__global__ __launch_bounds__(256) void pool_partial(
    const _Float16* __restrict__ h, const int* __restrict__ startg,
    const int* __restrict__ endg, float* __restrict__ sumP, float* __restrict__ maxP)
{
    __shared__ float4 sS[4][64];
    __shared__ float4 sM[4][64];
    int g = blockIdx.x >> 5, part = blockIdx.x & (NPART - 1);
    int lane = threadIdx.x & 63;
    int sub = threadIdx.x >> 6;
    int c0 = lane * 4;
    int s = startg[g], e = endg[g];
    float4 sum = make_float4(0.f, 0.f, 0.f, 0.f);
    float4 mx = make_float4(-INFINITY, -INFINITY, -INFINITY, -INFINITY);
    for (int i = s + part * 4 + sub; i < e; i += NPART * 4) {
        uint2 u = *(const uint2*)&h[(size_t)i * HCDIM + c0];
        h2 a = bch2(u.x), b = bch2(u.y);
        float4 v = make_float4((float)a.x, (float)a.y, (float)b.x, (float)b.y);
        sum.x += v.x; sum.y += v.y; sum.z += v.z; sum.w += v.w;
        mx.x = fmaxf(mx.x, v.x); mx.y = fmaxf(mx.y, v.y);
        mx.z = fmaxf(mx.z, v.z); mx.w = fmaxf(mx.w, v.w);
    }
    sS[sub][lane] = sum; sM[sub][lane] = mx;
    __syncthreads();
    if (sub == 0) {
        #pragma unroll
        for (int j = 1; j < 4; ++j) {
            float4 a = sS[j][lane], b = sM[j][lane];
            sum.x += a.x; sum.y += a.y; sum.z += a.z; sum.w += a.w;
            mx.x = fmaxf(mx.x, b.x); mx.y = fmaxf(mx.y, b.y);
            mx.z = fmaxf(mx.z, b.z); mx.w = fmaxf(mx.w, b.w);
        }
        size_t o = (size_t)blockIdx.x * HCDIM + c0;
        *(float4*)&sumP[o] = sum;
        *(float4*)&maxP[o] = mx;
    }
}

// Stage 2 + logits + softmax fused
__global__ __launch_bounds__(256) void pool_final_logits(
    const float* __restrict__ sumP, const float* __restrict__ maxP,
    const int* __restrict__ startg, const int* __restrict__ endg,
    const float* __restrict__ Wout, const float* __restrict__ bout,
    float* __restrict__ out)
{
    __shared__ float red[256];
    __shared__ float lg[NCLS];
    int g = blockIdx.x, c = threadIdx.x;
    float s = 0.f, m = -INFINITY;
    #pragma unroll 8
    for (int part = 0; part < NPART; ++part) {
        size_t o = (size_t)(g * NPART + part) * HCDIM + c;
        s += sumP[o];
        m = fmaxf(m, maxP[o]);
    }
    int cnt = endg[g] - startg[g];
    float inv = 1.f / fmaxf((float)cnt, 1.f);
    float pv = s * inv + m;

    for (int j = 0; j < NCLS; ++j) {
        red[c] = pv * Wout[c * NCLS + j];
        __syncthreads();
        for (int off = 128; off > 0; off >>= 1) {
            if (c < off) red[c] += red[c + off];
            __syncthreads();
        }
        if (c == 0) lg[j] = red[0] + bout[j];
        __syncthreads();
    }
    if (c == 0) {
        float mx = fmaxf(lg[0], fmaxf(lg[1], lg[2]));
        float e0 = __expf(lg[0] - mx), e1 = __expf(lg[1] - mx), e2 = __expf(lg[2] - mx);
        float invs = 1.f / (e0 + e1 + e2);
        out[g * NCLS + 0] = e0 * invs;
        out[g * NCLS + 1] = e1 * invs;
        out[g * NCLS + 2] = e2 * invs;
    }
}

// ============================ Orchestration ============================
extern "C" void kernel_launch(void* const* d_in, const int* in_sizes, int n_in,
                              void* d_out, int out_size, void* d_ws, size_t ws_size,
                              hipStream_t stream) {
    const float* x     = (const float*)d_in[0];
    const int*   ei    = (const int*)d_in[1];
    const int*   batch = (const int*)d_in[2];
    const float *Wl[3], *bl[3], *Wr[3], *br[3], *att[3], *bias[3];
    for (int li = 0; li < 3; ++li) {
        int b = 3 + li * 6;
        Wl[li]   = (const float*)d_in[b + 0];
        bl[li]   = (const float*)d_in[b + 1];
        Wr[li]   = (const float*)d_in[b + 2];
        br[li]   = (const float*)d_in[b + 3];
        att[li]  = (const float*)d_in[b + 4];
        bias[li] = (const float*)d_in[b + 5];
    }
    const float* Wout = (const float*)d_in[21];
    const float* bout = (const float*)d_in[22];
    float* out = (float*)d_out;

    size_t off = 0;
    char* wsb = (char*)d_ws;
    auto alloc = [&](size_t bytes) -> char* {
        char* ptr = wsb + off;
        off += (bytes + 255) & ~(size_t)255;
        return ptr;
    };
    int* zblk    = (int*)alloc((N_NODES + 2 * NGRAPH) * sizeof(int));
    int* deg     = zblk;
    int* startg  = zblk + N_NODES;
    int* endg    = zblk + N_NODES + NGRAPH;
    int* rowptr  = (int*)alloc((N_NODES + 1) * sizeof(int));
    int* cursor  = (int*)alloc(N_NODES * sizeof(int));
    int* bsums   = (int*)alloc(256 * sizeof(int));
    int* colx    = (int*)alloc((size_t)(N_EDGES + N_NODES + 8) * sizeof(int));
    _Float16* Abuf = (_Float16*)alloc((size_t)MPAD * HCDIM * sizeof(_Float16));
    _Float16* Bt[3];
    for (int li = 0; li < 3; ++li) {
        int K = (li == 0) ? F_INPUT : HCDIM;
        Bt[li] = (_Float16*)alloc((size_t)512 * K * sizeof(_Float16));
    }
    unsigned char* xl8 = (unsigned char*)alloc((size_t)N_NODES * HCDIM);
    _Float16* xrh  = (_Float16*)alloc((size_t)N_NODES * HCDIM * sizeof(_Float16));
    _Float16* hbuf = (_Float16*)alloc((size_t)N_NODES * HCDIM * sizeof(_Float16));
    float* sumP    = (float*)alloc((size_t)NGRAPH * NPART * HCDIM * sizeof(float));
    float* maxP    = (float*)alloc((size_t)NGRAPH * NPART * HCDIM * sizeof(float));

    hipMemsetAsync(zblk, 0, (N_NODES + 2 * NGRAPH) * sizeof(int), stream);

    hist_boundary_kernel<<<HIST_NB + BND_NB, 256, 0, stream>>>(ei, deg, batch, startg, endg);
    block_scan_kernel<<<SCAN_NB, 256, 0, stream>>>(deg, rowptr, bsums);
    add_off_kernel<<<SCAN_NB, 256, 0, stream>>>(rowptr, cursor, bsums);
    fill_kernel<<<(N_EDGES + N_NODES + 8 + 255) / 256, 256, 0, stream>>>(ei, cursor, colx);

    prep_kernel<<<PREP_NB, 256, 0, stream>>>(x, Abuf, Bt[0], Bt[1], Bt[2],
                                             Wl[0], Wr[0], Wl[1], Wr[1], Wl[2], Wr[2]);

    for (int li = 0; li < 3; ++li) {
        int K = (li == 0) ? F_INPUT : HCDIM;
        gemm_mfma<<<(MPAD / 64) * 4, 256, 0, stream>>>(
            Abuf, Bt[li], K, bl[li], br[li], xl8, xrh);
        if (li < 2) {
            gat_edge<<<N_NODES / 4, 256, 0, stream>>>(
                xl8, xrh, att[li], bias[li], rowptr, colx, nullptr, Abuf, 1);
        } else {
            gat_edge<<<N_NODES / 4, 256, 0, stream>>>(
                xl8, xrh, att[li], bias[li], rowptr, colx, hbuf, nullptr, 0);
        }
    }

    pool_partial<<<NGRAPH * NPART, 256, 0, stream>>>(hbuf, startg, endg, sumP, maxP);
    pool_final_logits<<<NGRAPH, 256, 0, stream>>>(sumP, maxP, startg, endg, Wout, bout, out);
}